// Round 1
// 214.410 us; speedup vs baseline: 1.1021x; 1.1021x over previous
//
#include <hip/hip_runtime.h>
#include <hip/hip_bf16.h>

// GCN 2-layer, slack-bucket dst-radix-sort + batched wave gathers:
//   fused dispatch: blocks [0,pblocks) partition edges into slack bucket
//     regions (b*cap, alloc via gcursor atomics); blocks [pblocks,..) do
//     h1 = bf16(bf16(x) @ bf16(W1)) via MFMA 16x16x32
//   sort2: per-bucket counting sort by dst&255 -> es2 (+ per-node int2 seg)
//   gather1 (batched, LDS edge staging): 16 lanes/row dwordx2 gathers,
//     16 edges/iter clamp-masked (no serial tail); layer2 via MFMA
//   gather2 (batched, LDS edge staging): 8 lanes/row dwordx2 gathers,
//     32 edges/iter clamp-masked; out = segsum(h2[src]*w) + b2 (f32)

typedef unsigned short u16;
typedef unsigned int uint;
typedef short short8 __attribute__((ext_vector_type(8)));
typedef float floatx4 __attribute__((ext_vector_type(4)));

static __device__ __forceinline__ u16 f2bf(float f) {
    unsigned int u = __float_as_uint(f);
    return (u16)((u + 0x7fff + ((u >> 16) & 1)) >> 16);   // RNE
}

#define F4C(v, j) ((j)==0?(v).x:((j)==1?(v).y:((j)==2?(v).z:(v).w)))
#define CHUNK 4096
#define ECAP 384   // per-wave LDS edge-buffer capacity (mean 256, +8 sigma)

// ------- fused: partition (blocks 0..pblocks-1) + GEMM h1=x@W1 (rest) -------
// edge entry: x = src | (dst&255)<<24 ; y = w bits
union SharedU {
    struct {                                   // GEMM part (33.4 KB)
        u16 xs[64][136];
        u16 wf[4][4][64][8];                   // [ntile][step][lane][j]
    } g;
    struct {                                   // partition part (50 KB)
        int2 stage[CHUNK];                     // 32 KB
        u16  stb[CHUNK];                       // 8 KB
        int  hist[512], sc[512], xscan[512], place[512], runbase[512];
    } p;
};

__global__ __launch_bounds__(256, 3) void g1p_kernel(
    const float* __restrict__ x, const float* __restrict__ W1,
    u16* __restrict__ h1, int N,
    const int* __restrict__ src, const int* __restrict__ dst,
    const float* __restrict__ w, int* __restrict__ gcursor,
    int2* __restrict__ es, int E, int cap, int pblocks)
{
    __shared__ SharedU sh;
    const int tid = threadIdx.x;

    if (blockIdx.x < pblocks) {            // ---------- partition ----------
        const int base = blockIdx.x * CHUNK;
        const int nloc = min(CHUNK, E - base);

        sh.p.hist[tid] = 0; sh.p.hist[tid + 256] = 0;
        __syncthreads();
        for (int i = tid; i < nloc; i += 256)
            atomicAdd(&sh.p.hist[dst[base + i] >> 8], 1);
        __syncthreads();

        sh.p.sc[tid] = sh.p.hist[tid];
        sh.p.sc[tid + 256] = sh.p.hist[tid + 256];
        __syncthreads();
        for (int o = 1; o < 512; o <<= 1) {          // inclusive scan, 512 wide
            int v0 = (tid >= o) ? sh.p.sc[tid - o] : 0;
            int v1 = (tid + 256 >= o) ? sh.p.sc[tid + 256 - o] : 0;
            __syncthreads();
            sh.p.sc[tid] += v0;
            sh.p.sc[tid + 256] += v1;
            __syncthreads();
        }
        sh.p.xscan[tid] = sh.p.sc[tid] - sh.p.hist[tid];
        sh.p.xscan[tid + 256] = sh.p.sc[tid + 256] - sh.p.hist[tid + 256];
        sh.p.place[tid] = sh.p.xscan[tid];
        sh.p.place[tid + 256] = sh.p.xscan[tid + 256];
        __syncthreads();

        for (int i = tid; i < nloc; i += 256) {      // group by bucket in LDS
            int d = dst[base + i];
            int b = d >> 8;
            int pos = atomicAdd(&sh.p.place[b], 1);
            sh.p.stage[pos] = make_int2(src[base + i] | ((d & 255) << 24),
                                        __float_as_int(w[base + i]));
            sh.p.stb[pos] = (u16)b;
        }
        __syncthreads();

        {   // reserve runs in slack regions
            int l0 = sh.p.hist[tid], l1 = sh.p.hist[tid + 256];
            sh.p.runbase[tid]       = l0 ? atomicAdd(&gcursor[tid], l0)       : 0;
            sh.p.runbase[tid + 256] = l1 ? atomicAdd(&gcursor[tid + 256], l1) : 0;
        }
        __syncthreads();

        for (int i = tid; i < nloc; i += 256) {      // contiguous run writes
            int b = sh.p.stb[i];
            es[(size_t)b * cap + sh.p.runbase[b] + (i - sh.p.xscan[b])] = sh.p.stage[i];
        }
        return;
    }

    // ---------- GEMM ----------
    const int row0 = (blockIdx.x - pblocks) * 64;
    {   // stage W1 (128x64 f32) -> bf16, swizzled to B-fragment order
        const float4* W4 = (const float4*)W1;
        #pragma unroll
        for (int i = 0; i < 8; i++) {
            int idx = tid + i*256;
            int k = idx >> 4, n4 = (idx & 15) * 4;
            float4 v = W4[idx];
            int step = k >> 5, klane = (k >> 3) & 3, j = k & 7;
            #pragma unroll
            for (int c = 0; c < 4; c++) {
                int n = n4 + c;
                sh.g.wf[n >> 4][step][klane*16 + (n & 15)][j] = f2bf(F4C(v, c));
            }
        }
    }
    {   // stage x tile -> bf16
        const float4* x4 = (const float4*)x;
        #pragma unroll
        for (int i = 0; i < 8; i++) {
            int idx = tid + i*256;
            int r = idx >> 5, kc = idx & 31;
            int gr = row0 + r;
            float4 v = make_float4(0.f,0.f,0.f,0.f);
            if (gr < N) v = x4[gr*32 + kc];
            ushort4 o;
            o.x = f2bf(v.x); o.y = f2bf(v.y); o.z = f2bf(v.z); o.w = f2bf(v.w);
            *(ushort4*)&sh.g.xs[r][kc*4] = o;
        }
    }
    __syncthreads();

    const int wave = tid >> 6, lane = tid & 63;
    const int m = lane & 15, quad = lane >> 4;
    const int rw = wave * 16;

    floatx4 acc[4] = {(floatx4)(0.f), (floatx4)(0.f), (floatx4)(0.f), (floatx4)(0.f)};
    #pragma unroll
    for (int step = 0; step < 4; step++) {
        short8 a = *(const short8*)&sh.g.xs[rw + m][step*32 + quad*8];
        #pragma unroll
        for (int nt = 0; nt < 4; nt++) {
            short8 b = *(const short8*)&sh.g.wf[nt][step][lane][0];
            acc[nt] = __builtin_amdgcn_mfma_f32_16x16x32_bf16(a, b, acc[nt], 0, 0, 0);
        }
    }
    #pragma unroll
    for (int nt = 0; nt < 4; nt++) {
        #pragma unroll
        for (int r = 0; r < 4; r++) {
            int gr = row0 + rw + quad*4 + r;
            if (gr < N) h1[(size_t)gr*64 + nt*16 + m] = f2bf(acc[nt][r]);
        }
    }
}

// ------- sort2: per-bucket single-pass counting sort (LDS-staged) -------
#define SCAP 6144
__global__ __launch_bounds__(512, 3) void sort2_kernel(
    const int2* __restrict__ es, const int* __restrict__ gcursor,
    int2* __restrict__ es2, int2* __restrict__ off2, int N, int cap, int nb)
{
    __shared__ int2 stage[SCAP];                  // 48 KB
    __shared__ int hist[256], sc[256], cur[256];
    const int t = threadIdx.x;
    const int b = blockIdx.x;
    const int e0 = b * cap;
    const int len = gcursor[b];
    const int nstage = min(len, SCAP);

    if (t < 256) hist[t] = 0;
    __syncthreads();
    for (int i = t; i < nstage; i += 512) {       // stage + hist in one pass
        int2 e = es[e0 + i];
        stage[i] = e;
        atomicAdd(&hist[((unsigned)e.x) >> 24], 1);
    }
    for (int i = SCAP + t; i < len; i += 512)     // overflow: hist from global
        atomicAdd(&hist[((unsigned)es[e0 + i].x) >> 24], 1);
    __syncthreads();

    int v = 0;
    if (t < 256) { v = hist[t]; sc[t] = v; }
    __syncthreads();
    for (int o = 1; o < 256; o <<= 1) {
        int add = 0;
        if (t < 256 && t >= o) add = sc[t - o];
        __syncthreads();
        if (t < 256) sc[t] += add;
        __syncthreads();
    }
    if (t < 256) {
        int ex = sc[t] - v;                       // exclusive within bucket
        cur[t] = ex;
        int g = b * 256 + t;
        if (g < N) off2[g] = make_int2(e0 + ex, e0 + ex + v);
    }
    __syncthreads();

    for (int i = t; i < nstage; i += 512) {
        int2 e = stage[i];
        int pos = e0 + atomicAdd(&cur[((unsigned)e.x) >> 24], 1);
        es2[pos] = e;                             // scatter within 36 KB window
    }
    for (int i = SCAP + t; i < len; i += 512) {   // overflow scatter
        int2 e = es[e0 + i];
        int pos = e0 + atomicAdd(&cur[((unsigned)e.x) >> 24], 1);
        es2[pos] = e;
    }
}

// ------- gather1 batched: 64 nodes/block, wave stages its contiguous edge
//   range into LDS, gathers 16 nodes. 16 lanes/row (dwordx2), 4 edge slots,
//   16 edges/iter clamp-masked; layer2 (relu(+b1) @ W2) via MFMA -------------
__global__ __launch_bounds__(256, 6) void gather1_kernel(
    const u16* __restrict__ h1, const int2* __restrict__ es,
    const int2* __restrict__ off2, const float* __restrict__ b1,
    const float* __restrict__ W2, u16* __restrict__ h2, int N)
{
    __shared__ __align__(16) u16 ts[64][72];          // t rows, bf16 (144B rows)
    __shared__ __align__(16) u16 wf2[2][2][64][8];    // [ntile][step][lane][j]
    __shared__ float b1s[64];
    __shared__ int2 eb[4][ECAP];                      // per-wave edge buffer
    const int tid = threadIdx.x;

    {   // stage W2 (64x32 f32 = 512 float4) -> bf16 B-fragments, + b1
        const float4* s4 = (const float4*)W2;
        #pragma unroll
        for (int i = 0; i < 2; i++) {
            int idx = tid + i*256;
            float4 v = s4[idx];
            int k = idx >> 3, n4 = (idx & 7) * 4;
            int step = k >> 5, quad = (k >> 3) & 3, j = k & 7;
            #pragma unroll
            for (int c = 0; c < 4; c++) {
                int n = n4 + c;
                wf2[n >> 4][step][quad*16 + (n & 15)][j] = f2bf(F4C(v, c));
            }
        }
        if (tid < 16) ((float4*)b1s)[tid] = ((const float4*)b1)[tid];
    }
    __syncthreads();

    const int wave = tid >> 6, lane = tid & 63;
    const int h = lane >> 4, fl = lane & 15;          // slot 0..3, ch-group 0..15
    const int node0 = blockIdx.x * 64 + wave * 16;
    const uint2* h1v = (const uint2*)h1;   // h1 row = 16 uint2 (64 bf16, 128B)
    uint* tsu = (uint*)&ts[0][0];          // rows of 36 uints

    // prefetch segments (lanes 0..15; clamp keeps OOB waves harmless)
    const int2 sg = off2[min(node0 + fl, N - 1)];
    const int beg = __builtin_amdgcn_readfirstlane(sg.x);
    const int end = __builtin_amdgcn_readlane(sg.y, 15);
    const int len = end - beg;

    if (len <= ECAP) {
        // ---- stage wave's whole edge range into LDS (coalesced) ----
        for (int k = lane; k < len; k += 64) eb[wave][k] = es[beg + k];
        // intra-wave LDS write->read ordering: compiler lgkmcnt

        #pragma unroll 1
        for (int i = 0; i < 16; i++) {
            const int pbeg = __builtin_amdgcn_readlane(sg.x, i) - beg;
            const int pend = __builtin_amdgcn_readlane(sg.y, i) - beg;
            const int cl = pend - 1;
            float a0 = 0.f, a1 = 0.f, a2 = 0.f, a3 = 0.f;
            #pragma unroll 1
            for (int p = pbeg; p < pend; p += 16) {   // 16 edges, 4 loads in flight
                const int i0 = p + h, i1 = p + 4 + h, i2 = p + 8 + h, i3 = p + 12 + h;
                int2 e0 = eb[wave][min(i0, cl)];
                int2 e1 = eb[wave][min(i1, cl)];
                int2 e2 = eb[wave][min(i2, cl)];
                int2 e3 = eb[wave][min(i3, cl)];
                uint2 v0 = h1v[(size_t)(e0.x & 0xFFFFFF) * 16 + fl];
                uint2 v1 = h1v[(size_t)(e1.x & 0xFFFFFF) * 16 + fl];
                uint2 v2 = h1v[(size_t)(e2.x & 0xFFFFFF) * 16 + fl];
                uint2 v3 = h1v[(size_t)(e3.x & 0xFFFFFF) * 16 + fl];
                float w0 = (i0 < pend) ? __int_as_float(e0.y) : 0.f;
                float w1 = (i1 < pend) ? __int_as_float(e1.y) : 0.f;
                float w2 = (i2 < pend) ? __int_as_float(e2.y) : 0.f;
                float w3 = (i3 < pend) ? __int_as_float(e3.y) : 0.f;
                a0 += __uint_as_float(v0.x << 16) * w0 + __uint_as_float(v1.x << 16) * w1
                    + __uint_as_float(v2.x << 16) * w2 + __uint_as_float(v3.x << 16) * w3;
                a1 += __uint_as_float(v0.x & 0xFFFF0000u) * w0 + __uint_as_float(v1.x & 0xFFFF0000u) * w1
                    + __uint_as_float(v2.x & 0xFFFF0000u) * w2 + __uint_as_float(v3.x & 0xFFFF0000u) * w3;
                a2 += __uint_as_float(v0.y << 16) * w0 + __uint_as_float(v1.y << 16) * w1
                    + __uint_as_float(v2.y << 16) * w2 + __uint_as_float(v3.y << 16) * w3;
                a3 += __uint_as_float(v0.y & 0xFFFF0000u) * w0 + __uint_as_float(v1.y & 0xFFFF0000u) * w1
                    + __uint_as_float(v2.y & 0xFFFF0000u) * w2 + __uint_as_float(v3.y & 0xFFFF0000u) * w3;
            }
            a0 += __shfl_xor(a0, 16, 64); a1 += __shfl_xor(a1, 16, 64);
            a2 += __shfl_xor(a2, 16, 64); a3 += __shfl_xor(a3, 16, 64);
            a0 += __shfl_xor(a0, 32, 64); a1 += __shfl_xor(a1, 32, 64);
            a2 += __shfl_xor(a2, 32, 64); a3 += __shfl_xor(a3, 32, 64);
            if (h == 0) {
                uint t0 = (uint)f2bf(fmaxf(a0 + b1s[4*fl],     0.f))
                        | ((uint)f2bf(fmaxf(a1 + b1s[4*fl + 1], 0.f)) << 16);
                uint t1 = (uint)f2bf(fmaxf(a2 + b1s[4*fl + 2], 0.f))
                        | ((uint)f2bf(fmaxf(a3 + b1s[4*fl + 3], 0.f)) << 16);
                *(uint2*)&tsu[(wave*16 + i) * 36 + 2*fl] = make_uint2(t0, t1);
            }
        }
    } else {
        // ---- overflow fallback: direct global edge reads (never in practice)
        #pragma unroll 1
        for (int i = 0; i < 16; i++) {
            const int pbeg = __builtin_amdgcn_readlane(sg.x, i);
            const int pend = __builtin_amdgcn_readlane(sg.y, i);
            const int cl = pend - 1;
            float a0 = 0.f, a1 = 0.f, a2 = 0.f, a3 = 0.f;
            #pragma unroll 1
            for (int p = pbeg; p < pend; p += 16) {
                const int i0 = p + h, i1 = p + 4 + h, i2 = p + 8 + h, i3 = p + 12 + h;
                int2 e0 = es[min(i0, cl)];
                int2 e1 = es[min(i1, cl)];
                int2 e2 = es[min(i2, cl)];
                int2 e3 = es[min(i3, cl)];
                uint2 v0 = h1v[(size_t)(e0.x & 0xFFFFFF) * 16 + fl];
                uint2 v1 = h1v[(size_t)(e1.x & 0xFFFFFF) * 16 + fl];
                uint2 v2 = h1v[(size_t)(e2.x & 0xFFFFFF) * 16 + fl];
                uint2 v3 = h1v[(size_t)(e3.x & 0xFFFFFF) * 16 + fl];
                float w0 = (i0 < pend) ? __int_as_float(e0.y) : 0.f;
                float w1 = (i1 < pend) ? __int_as_float(e1.y) : 0.f;
                float w2 = (i2 < pend) ? __int_as_float(e2.y) : 0.f;
                float w3 = (i3 < pend) ? __int_as_float(e3.y) : 0.f;
                a0 += __uint_as_float(v0.x << 16) * w0 + __uint_as_float(v1.x << 16) * w1
                    + __uint_as_float(v2.x << 16) * w2 + __uint_as_float(v3.x << 16) * w3;
                a1 += __uint_as_float(v0.x & 0xFFFF0000u) * w0 + __uint_as_float(v1.x & 0xFFFF0000u) * w1
                    + __uint_as_float(v2.x & 0xFFFF0000u) * w2 + __uint_as_float(v3.x & 0xFFFF0000u) * w3;
                a2 += __uint_as_float(v0.y << 16) * w0 + __uint_as_float(v1.y << 16) * w1
                    + __uint_as_float(v2.y << 16) * w2 + __uint_as_float(v3.y << 16) * w3;
                a3 += __uint_as_float(v0.y & 0xFFFF0000u) * w0 + __uint_as_float(v1.y & 0xFFFF0000u) * w1
                    + __uint_as_float(v2.y & 0xFFFF0000u) * w2 + __uint_as_float(v3.y & 0xFFFF0000u) * w3;
            }
            a0 += __shfl_xor(a0, 16, 64); a1 += __shfl_xor(a1, 16, 64);
            a2 += __shfl_xor(a2, 16, 64); a3 += __shfl_xor(a3, 16, 64);
            a0 += __shfl_xor(a0, 32, 64); a1 += __shfl_xor(a1, 32, 64);
            a2 += __shfl_xor(a2, 32, 64); a3 += __shfl_xor(a3, 32, 64);
            if (h == 0) {
                uint t0 = (uint)f2bf(fmaxf(a0 + b1s[4*fl],     0.f))
                        | ((uint)f2bf(fmaxf(a1 + b1s[4*fl + 1], 0.f)) << 16);
                uint t1 = (uint)f2bf(fmaxf(a2 + b1s[4*fl + 2], 0.f))
                        | ((uint)f2bf(fmaxf(a3 + b1s[4*fl + 3], 0.f)) << 16);
                *(uint2*)&tsu[(wave*16 + i) * 36 + 2*fl] = make_uint2(t0, t1);
            }
        }
    }

    // layer2 MFMA on this wave's own 16 rows (intra-wave LDS dep, in-order)
    const int m = lane & 15, quad = lane >> 4;
    floatx4 acc[2] = {(floatx4)(0.f), (floatx4)(0.f)};
    #pragma unroll
    for (int step = 0; step < 2; step++) {
        short8 a = *(const short8*)&ts[wave*16 + m][step*32 + quad*8];
        #pragma unroll
        for (int nt = 0; nt < 2; nt++) {
            short8 b = *(const short8*)&wf2[nt][step][lane][0];
            acc[nt] = __builtin_amdgcn_mfma_f32_16x16x32_bf16(a, b, acc[nt], 0, 0, 0);
        }
    }
    #pragma unroll
    for (int nt = 0; nt < 2; nt++) {
        #pragma unroll
        for (int r = 0; r < 4; r++) {
            int g = node0 + quad*4 + r;
            if (g < N) h2[(size_t)g*32 + nt*16 + m] = f2bf(acc[nt][r]);
        }
    }
}

// ------- gather2 batched: 16 nodes/wave, LDS edge staging, 8 lanes/row
//   (dwordx2), 8 edge slots, 32 edges/iter clamp-masked --------------------
__global__ __launch_bounds__(256) void gather2_kernel(
    const u16* __restrict__ h2, const int2* __restrict__ es,
    const int2* __restrict__ off2, const float* __restrict__ b2,
    float* __restrict__ out, int N)
{
    __shared__ int2 eb[4][ECAP];
    const int tid = threadIdx.x;
    const int wave = tid >> 6, lane = tid & 63;
    const int g = lane >> 3, fl = lane & 7;           // slot 0..7, ch-group 0..7
    const int node0 = blockIdx.x * 64 + wave * 16;
    const uint2* h2v = (const uint2*)h2;   // h2 row = 8 uint2 (32 bf16, 64B)

    const int2 sg = off2[min(node0 + (lane & 15), N - 1)];
    const int beg = __builtin_amdgcn_readfirstlane(sg.x);
    const int end = __builtin_amdgcn_readlane(sg.y, 15);
    const int len = end - beg;
    const float4 bb = ((const float4*)b2)[fl];

    if (len <= ECAP) {
        for (int k = lane; k < len; k += 64) eb[wave][k] = es[beg + k];

        #pragma unroll 1
        for (int i = 0; i < 16; i++) {
            const int pbeg = __builtin_amdgcn_readlane(sg.x, i) - beg;
            const int pend = __builtin_amdgcn_readlane(sg.y, i) - beg;
            const int cl = pend - 1;
            float a0 = 0.f, a1 = 0.f, a2 = 0.f, a3 = 0.f;
            #pragma unroll 1
            for (int p = pbeg; p < pend; p += 32) {   // 32 edges, 4 loads in flight
                const int i0 = p + g, i1 = p + 8 + g, i2 = p + 16 + g, i3 = p + 24 + g;
                int2 e0 = eb[wave][min(i0, cl)];
                int2 e1 = eb[wave][min(i1, cl)];
                int2 e2 = eb[wave][min(i2, cl)];
                int2 e3 = eb[wave][min(i3, cl)];
                uint2 v0 = h2v[(size_t)(e0.x & 0xFFFFFF) * 8 + fl];
                uint2 v1 = h2v[(size_t)(e1.x & 0xFFFFFF) * 8 + fl];
                uint2 v2 = h2v[(size_t)(e2.x & 0xFFFFFF) * 8 + fl];
                uint2 v3 = h2v[(size_t)(e3.x & 0xFFFFFF) * 8 + fl];
                float w0 = (i0 < pend) ? __int_as_float(e0.y) : 0.f;
                float w1 = (i1 < pend) ? __int_as_float(e1.y) : 0.f;
                float w2 = (i2 < pend) ? __int_as_float(e2.y) : 0.f;
                float w3 = (i3 < pend) ? __int_as_float(e3.y) : 0.f;
                a0 += __uint_as_float(v0.x << 16) * w0 + __uint_as_float(v1.x << 16) * w1
                    + __uint_as_float(v2.x << 16) * w2 + __uint_as_float(v3.x << 16) * w3;
                a1 += __uint_as_float(v0.x & 0xFFFF0000u) * w0 + __uint_as_float(v1.x & 0xFFFF0000u) * w1
                    + __uint_as_float(v2.x & 0xFFFF0000u) * w2 + __uint_as_float(v3.x & 0xFFFF0000u) * w3;
                a2 += __uint_as_float(v0.y << 16) * w0 + __uint_as_float(v1.y << 16) * w1
                    + __uint_as_float(v2.y << 16) * w2 + __uint_as_float(v3.y << 16) * w3;
                a3 += __uint_as_float(v0.y & 0xFFFF0000u) * w0 + __uint_as_float(v1.y & 0xFFFF0000u) * w1
                    + __uint_as_float(v2.y & 0xFFFF0000u) * w2 + __uint_as_float(v3.y & 0xFFFF0000u) * w3;
            }
            a0 += __shfl_xor(a0, 8, 64);  a1 += __shfl_xor(a1, 8, 64);
            a2 += __shfl_xor(a2, 8, 64);  a3 += __shfl_xor(a3, 8, 64);
            a0 += __shfl_xor(a0, 16, 64); a1 += __shfl_xor(a1, 16, 64);
            a2 += __shfl_xor(a2, 16, 64); a3 += __shfl_xor(a3, 16, 64);
            a0 += __shfl_xor(a0, 32, 64); a1 += __shfl_xor(a1, 32, 64);
            a2 += __shfl_xor(a2, 32, 64); a3 += __shfl_xor(a3, 32, 64);
            const int d = node0 + i;
            if (g == 0 && d < N)
                *(float4*)&out[(size_t)d * 32 + 4 * fl] =
                    make_float4(a0 + bb.x, a1 + bb.y, a2 + bb.z, a3 + bb.w);
        }
    } else {
        #pragma unroll 1
        for (int i = 0; i < 16; i++) {
            const int pbeg = __builtin_amdgcn_readlane(sg.x, i);
            const int pend = __builtin_amdgcn_readlane(sg.y, i);
            const int cl = pend - 1;
            float a0 = 0.f, a1 = 0.f, a2 = 0.f, a3 = 0.f;
            #pragma unroll 1
            for (int p = pbeg; p < pend; p += 32) {
                const int i0 = p + g, i1 = p + 8 + g, i2 = p + 16 + g, i3 = p + 24 + g;
                int2 e0 = es[min(i0, cl)];
                int2 e1 = es[min(i1, cl)];
                int2 e2 = es[min(i2, cl)];
                int2 e3 = es[min(i3, cl)];
                uint2 v0 = h2v[(size_t)(e0.x & 0xFFFFFF) * 8 + fl];
                uint2 v1 = h2v[(size_t)(e1.x & 0xFFFFFF) * 8 + fl];
                uint2 v2 = h2v[(size_t)(e2.x & 0xFFFFFF) * 8 + fl];
                uint2 v3 = h2v[(size_t)(e3.x & 0xFFFFFF) * 8 + fl];
                float w0 = (i0 < pend) ? __int_as_float(e0.y) : 0.f;
                float w1 = (i1 < pend) ? __int_as_float(e1.y) : 0.f;
                float w2 = (i2 < pend) ? __int_as_float(e2.y) : 0.f;
                float w3 = (i3 < pend) ? __int_as_float(e3.y) : 0.f;
                a0 += __uint_as_float(v0.x << 16) * w0 + __uint_as_float(v1.x << 16) * w1
                    + __uint_as_float(v2.x << 16) * w2 + __uint_as_float(v3.x << 16) * w3;
                a1 += __uint_as_float(v0.x & 0xFFFF0000u) * w0 + __uint_as_float(v1.x & 0xFFFF0000u) * w1
                    + __uint_as_float(v2.x & 0xFFFF0000u) * w2 + __uint_as_float(v3.x & 0xFFFF0000u) * w3;
                a2 += __uint_as_float(v0.y << 16) * w0 + __uint_as_float(v1.y << 16) * w1
                    + __uint_as_float(v2.y << 16) * w2 + __uint_as_float(v3.y << 16) * w3;
                a3 += __uint_as_float(v0.y & 0xFFFF0000u) * w0 + __uint_as_float(v1.y & 0xFFFF0000u) * w1
                    + __uint_as_float(v2.y & 0xFFFF0000u) * w2 + __uint_as_float(v3.y & 0xFFFF0000u) * w3;
            }
            a0 += __shfl_xor(a0, 8, 64);  a1 += __shfl_xor(a1, 8, 64);
            a2 += __shfl_xor(a2, 8, 64);  a3 += __shfl_xor(a3, 8, 64);
            a0 += __shfl_xor(a0, 16, 64); a1 += __shfl_xor(a1, 16, 64);
            a2 += __shfl_xor(a2, 16, 64); a3 += __shfl_xor(a3, 16, 64);
            a0 += __shfl_xor(a0, 32, 64); a1 += __shfl_xor(a1, 32, 64);
            a2 += __shfl_xor(a2, 32, 64); a3 += __shfl_xor(a3, 32, 64);
            const int d = node0 + i;
            if (g == 0 && d < N)
                *(float4*)&out[(size_t)d * 32 + 4 * fl] =
                    make_float4(a0 + bb.x, a1 + bb.y, a2 + bb.z, a3 + bb.w);
        }
    }
}

extern "C" void kernel_launch(void* const* d_in, const int* in_sizes, int n_in,
                              void* d_out, int out_size, void* d_ws, size_t ws_size,
                              hipStream_t stream)
{
    const float* x   = (const float*)d_in[0];
    const int*  esrc = (const int*)d_in[1];
    const int*  edst = (const int*)d_in[2];
    const float* ew  = (const float*)d_in[3];
    const float* W1  = (const float*)d_in[4];
    const float* b1  = (const float*)d_in[5];
    const float* W2  = (const float*)d_in[6];
    const float* b2  = (const float*)d_in[7];
    float* out = (float*)d_out;

    const int N = in_sizes[0] / 128;   // 100000
    const int E = in_sizes[1];         // 1600000
    const int nb = (N + 255) >> 8;     // 391 buckets

    // slack bucket capacity: mean + ~8 sigma, 16-aligned
    const int mean = (E + nb - 1) / nb;
    int s = 1; while (s * s < mean) s++;                  // ceil sqrt
    const int cap = (mean + 8 * s + 15) & ~15;            // ~4608

    char* base = (char*)d_ws;
    size_t o = 0;
    auto alloc = [&](size_t bytes) { char* p = base + o; o = (o + bytes + 255) & ~(size_t)255; return p; };
    u16*  h1      = (u16*) alloc((size_t)N * 64 * 2);
    u16*  h2      = (u16*) alloc((size_t)N * 32 * 2);
    int2* es      = (int2*)alloc((size_t)nb * cap * 8);
    int2* es2     = (int2*)alloc((size_t)nb * cap * 8);
    int2* off2    = (int2*)alloc((size_t)N * 8);
    int*  gcursor = (int*) alloc(512 * 4);

    const int pblocks = (E + CHUNK - 1) / CHUNK;   // 391 partition blocks
    const int gblocks = (N + 63) / 64;             // 1563 gemm blocks

    hipMemsetAsync(gcursor, 0, 512 * 4, stream);
    g1p_kernel<<<pblocks + gblocks, 256, 0, stream>>>(
        x, W1, h1, N, esrc, edst, ew, gcursor, es, E, cap, pblocks);
    sort2_kernel<<<nb, 512, 0, stream>>>(es, gcursor, es2, off2, N, cap, nb);
    gather1_kernel<<<(N + 63) / 64, 256, 0, stream>>>(h1, es2, off2, b1, W2, h2, N);
    gather2_kernel<<<(N + 63) / 64, 256, 0, stream>>>(h2, es2, off2, b2, out, N);
}